// Round 8
// baseline (293.951 us; speedup 1.0000x reference)
//
#include <hip/hip_runtime.h>
#include <math.h>

#define N_NODES 50000
#define N_EDGES 800000
#define IN_CH   256
#define OUT_CH  64
#define HEADS   4
#define NEG_SLOPE 0.2f
#define NCOLS   320           // W (256) || W_res (64)
#define NTILES  20            // NCOLS / 16
#define NKK     8             // IN_CH / 32
#define PACK_BLOCKS 40        // NKK*NTILES*64 / 256
#define GEMM_BLOCKS 782       // (N_NODES+63)/64
#define SCAN_BLOCKS 196       // (N_NODES+255)/256
#define SCAT_BLOCKS 3125      // N_EDGES/256
#define LOGIT_BLOCKS 12500    // N_NODES/4

typedef __attribute__((ext_vector_type(8))) short short8;
typedef __attribute__((ext_vector_type(4))) float f32x4;

__device__ __forceinline__ float lrelu(float v) {
    return v > 0.f ? v : NEG_SLOPE * v;
}
__device__ __forceinline__ unsigned bf16_rne(float f) {
    unsigned u = __float_as_uint(f);
    return (u + 0x7FFFu + ((u >> 16) & 1u)) >> 16;
}
__device__ __forceinline__ unsigned pack2(float lo, float hi) {
    return bf16_rne(lo) | (bf16_rne(hi) << 16);
}
__device__ __forceinline__ float bflo(unsigned u) { return __uint_as_float(u << 16); }
__device__ __forceinline__ float bfhi(unsigned u) { return __uint_as_float(u & 0xFFFF0000u); }
__device__ __forceinline__ short8 as_short8(uint4 u) {
    union { uint4 u4; short8 s8; } cv; cv.u4 = u; return cv.s8;
}

// ---------------------------------------------------------------------------
// prep: fused pack_B (blocks 0..39) + histogram + fill-zero (blocks 40..).
// ---------------------------------------------------------------------------
__global__ __launch_bounds__(256) void prep(
    const float* __restrict__ W, const float* __restrict__ Wres,
    uint4* __restrict__ Bp, const int* __restrict__ ei,
    int* __restrict__ cnt, int* __restrict__ fill)
{
    if (blockIdx.x < PACK_BLOCKS) {
        const int idx  = blockIdx.x * 256 + threadIdx.x;   // 0..10239
        const int kk   = idx / (NTILES * 64);
        const int rem  = idx - kk * (NTILES * 64);
        const int t    = rem >> 6;
        const int lane = rem & 63;
        const int colL = lane & 15, quad = lane >> 4;
        const int col  = t * 16 + colL;
        const int k0   = kk * 32 + quad * 8;
        float v[8];
        #pragma unroll
        for (int j = 0; j < 8; ++j) {
            const int k = k0 + j;
            v[j] = (col < IN_CH) ? W[(size_t)k * IN_CH + col]
                                 : Wres[(size_t)k * OUT_CH + (col - IN_CH)];
        }
        uint4 u;
        u.x = pack2(v[0], v[1]); u.y = pack2(v[2], v[3]);
        u.z = pack2(v[4], v[5]); u.w = pack2(v[6], v[7]);
        Bp[(kk * NTILES + t) * 64 + lane] = u;
    } else {
        const int e = (blockIdx.x - PACK_BLOCKS) * 256 + threadIdx.x;
        if (e < N_NODES) fill[e] = 0;
        if (e < N_EDGES) atomicAdd(&cnt[ei[N_EDGES + e]], 1);
    }
}

// ---------------------------------------------------------------------------
// gemm_scan: blocks [0,GEMM_BLOCKS) = MFMA node transform (NO logit epilogue
// -> LDS 32KB, lower VGPR); blocks [GEMM_BLOCKS,+SCAN_BLOCKS) = scan_local
// (independent of gemm; rides along to overlap + save a dispatch).
// gemm: wave wv owns col-tiles {wv,4+wv,8+wv,12+wv,16+wv} over 4 row-groups.
// C/D: col=lane&15, row=(lane>>4)*4+reg. xw2 uint2 = (h0,h1|h2,h3) bf16.
// ---------------------------------------------------------------------------
__global__ __launch_bounds__(256) void gemm_scan(
    const float* __restrict__ x, const uint4* __restrict__ Bp,
    uint2* __restrict__ xw2, float* __restrict__ xres,
    const int* __restrict__ cnt, int* __restrict__ lscan,
    int* __restrict__ bsum)
{
    __shared__ uint4 Alds[4 * NKK * 64];   // 32 KB
    __shared__ int ws[4];

    if (blockIdx.x >= GEMM_BLOCKS) {
        // ---- scan_local ----
        const int bid = blockIdx.x - GEMM_BLOCKS;
        const int t = threadIdx.x, lane = t & 63, w = t >> 6;
        const int i = bid * 256 + t;
        const int v = (i < N_NODES) ? cnt[i] : 0;
        int sc = v;
        #pragma unroll
        for (int off = 1; off < 64; off <<= 1) {
            const int n = __shfl_up(sc, off);
            if (lane >= off) sc += n;
        }
        if (lane == 63) ws[w] = sc;
        __syncthreads();
        int prefix = 0;
        for (int j = 0; j < w; ++j) prefix += ws[j];
        if (i < N_NODES) lscan[i] = prefix + sc - v;
        if (t == 255) bsum[bid] = prefix + sc;
        return;
    }

    const int tid = threadIdx.x;
    const int n0  = blockIdx.x * 64;

    #pragma unroll
    for (int i = 0; i < 8; ++i) {
        const int e    = i * 256 + tid;
        const int g    = e >> 9;
        const int kk   = (e >> 6) & 7;
        const int lane = e & 63;
        const int cL   = lane & 15, qd = lane >> 4;
        const int row  = n0 + g * 16 + cL;
        const int k0   = kk * 32 + qd * 8;
        uint4 u = make_uint4(0u, 0u, 0u, 0u);
        if (row < N_NODES) {
            const float4 a = *reinterpret_cast<const float4*>(x + (size_t)row * IN_CH + k0);
            const float4 b = *reinterpret_cast<const float4*>(x + (size_t)row * IN_CH + k0 + 4);
            u.x = pack2(a.x, a.y); u.y = pack2(a.z, a.w);
            u.z = pack2(b.x, b.y); u.w = pack2(b.z, b.w);
        }
        Alds[(g * NKK + kk) * 64 + lane] = u;
    }
    __syncthreads();

    const int lane = tid & 63;
    const int wv   = tid >> 6;
    const int colL = lane & 15, quad = lane >> 4;

    f32x4 acc[4][5];
    #pragma unroll
    for (int rg = 0; rg < 4; ++rg)
        #pragma unroll
        for (int j = 0; j < 5; ++j) acc[rg][j] = (f32x4){0.f, 0.f, 0.f, 0.f};

    for (int kk = 0; kk < NKK; ++kk) {
        uint4 bu[5];
        #pragma unroll
        for (int j = 0; j < 5; ++j)
            bu[j] = Bp[(kk * NTILES + j * 4 + wv) * 64 + lane];
        #pragma unroll
        for (int rg = 0; rg < 4; ++rg) {
            const short8 a = as_short8(Alds[(rg * NKK + kk) * 64 + lane]);
            #pragma unroll
            for (int j = 0; j < 5; ++j)
                acc[rg][j] = __builtin_amdgcn_mfma_f32_16x16x32_bf16(
                    a, as_short8(bu[j]), acc[rg][j], 0, 0, 0);
        }
    }

    #pragma unroll
    for (int rg = 0; rg < 4; ++rg) {
        #pragma unroll
        for (int r = 0; r < 4; ++r) {
            const int row = n0 + rg * 16 + quad * 4 + r;
            if (row < N_NODES) {
                xw2[(size_t)row * 64 + wv * 16 + colL] = make_uint2(
                    pack2(acc[rg][0][r], acc[rg][1][r]),
                    pack2(acc[rg][2][r], acc[rg][3][r]));
                xres[(size_t)row * OUT_CH + wv * 16 + colL] = acc[rg][4][r];
            }
        }
    }
}

// ---------------------------------------------------------------------------
// scatter_logits: blocks [0,SCAT_BLOCKS) = CSR scatter (inline 196-elem bsum
// scan per block, L2-hot, kills the scan_bsum dispatch); blocks
// [SCAT_BLOCKS,+LOGIT_BLOCKS) = attention logits from packed bf16 xw2
// (one wave per node; 8 butterfly dots). Both lean (LDS ~1KB, low VGPR) ->
// full occupancy for the atomic/random-write phase.
// ---------------------------------------------------------------------------
__global__ __launch_bounds__(256) void scatter_logits(
    const int* __restrict__ ei, const int* __restrict__ lscan,
    const int* __restrict__ bsum, int* __restrict__ fill,
    int* __restrict__ esrc,
    const uint2* __restrict__ xw2, const float* __restrict__ attS,
    const float* __restrict__ attD, float* __restrict__ asrc,
    float* __restrict__ adst)
{
    const int t = threadIdx.x;
    const int lane = t & 63, wv = t >> 6;

    if (blockIdx.x < SCAT_BLOCKS) {
        __shared__ int bsx[256];
        __shared__ int ws[4];
        // inline exclusive scan of bsum[0..195]
        const int v = (t < SCAN_BLOCKS) ? bsum[t] : 0;
        int sc = v;
        #pragma unroll
        for (int off = 1; off < 64; off <<= 1) {
            const int n = __shfl_up(sc, off);
            if (lane >= off) sc += n;
        }
        if (lane == 63) ws[wv] = sc;
        __syncthreads();
        int prefix = 0;
        for (int j = 0; j < wv; ++j) prefix += ws[j];
        bsx[t] = prefix + sc - v;
        __syncthreads();

        const int e = blockIdx.x * 256 + t;
        if (e < N_EDGES) {
            const int d = ei[N_EDGES + e];
            const int pos = atomicAdd(&fill[d], 1);
            esrc[lscan[d] + bsx[d >> 8] + pos] = ei[e];
        }
        return;
    }

    // ---- logits ----
    const int n = (blockIdx.x - SCAT_BLOCKS) * 4 + wv;   // exact: 12500*4=50000
    const uint2 v = xw2[(size_t)n * 64 + lane];
    const float h0 = bflo(v.x), h1 = bfhi(v.x), h2 = bflo(v.y), h3 = bfhi(v.y);
    float s0 = h0 * attS[lane],       s1 = h1 * attS[64 + lane];
    float s2 = h2 * attS[128 + lane], s3 = h3 * attS[192 + lane];
    float d0 = h0 * attD[lane],       d1 = h1 * attD[64 + lane];
    float d2 = h2 * attD[128 + lane], d3 = h3 * attD[192 + lane];
    #pragma unroll
    for (int off = 32; off >= 1; off >>= 1) {
        s0 += __shfl_xor(s0, off); s1 += __shfl_xor(s1, off);
        s2 += __shfl_xor(s2, off); s3 += __shfl_xor(s3, off);
        d0 += __shfl_xor(d0, off); d1 += __shfl_xor(d1, off);
        d2 += __shfl_xor(d2, off); d3 += __shfl_xor(d3, off);
    }
    if (lane == 0)
        *reinterpret_cast<float4*>(asrc + (size_t)n * 4) = make_float4(s0, s1, s2, s3);
    if (lane == 1)
        *reinterpret_cast<float4*>(adst + (size_t)n * 4) = make_float4(d0, d1, d2, d3);
}

// ---------------------------------------------------------------------------
// aggregate, single-pass, unnormalized head accumulators. Inline bsum scan
// (as scatter). Per 64-edge chunk: lane-parallel gather asrc + exp -> LDS
// stash; per edge: uniform-addr LDS broadcast + ONE dwordx2 gather + 4 fma.
// 4x unroll, w consumed per-edge to keep live regs low (latency-bound:
// occupancy > ILP; R6's 8x unroll at 48 VGPR/44% occ regressed).
// ---------------------------------------------------------------------------
__global__ __launch_bounds__(256) void aggregate(
    const int* __restrict__ esrc, const int* __restrict__ lscan,
    const int* __restrict__ bsum, const int* __restrict__ cnt,
    const float* __restrict__ asrc, const float* __restrict__ adst,
    const uint2* __restrict__ xw2, const float* __restrict__ xres,
    const float* __restrict__ bias, float* __restrict__ out)
{
    __shared__ float4 wbuf[4][64];
    __shared__ int    sbuf[4][64];
    __shared__ int    bsx[256];
    __shared__ int    ws[4];
    const int t = threadIdx.x;
    const int lane = t & 63;
    const int wv   = t >> 6;

    // inline exclusive scan of bsum[0..195]
    {
        const int v = (t < SCAN_BLOCKS) ? bsum[t] : 0;
        int sc = v;
        #pragma unroll
        for (int off = 1; off < 64; off <<= 1) {
            const int n = __shfl_up(sc, off);
            if (lane >= off) sc += n;
        }
        if (lane == 63) ws[wv] = sc;
        __syncthreads();
        int prefix = 0;
        for (int j = 0; j < wv; ++j) prefix += ws[j];
        bsx[t] = prefix + sc - v;
        __syncthreads();
    }

    const int d = blockIdx.x * 4 + wv;                   // exact: 12500*4=50000
    const int row = lscan[d] + bsx[d >> 8];
    const int deg = cnt[d];
    const float4 ad = *reinterpret_cast<const float4*>(adst + (size_t)d * 4);
    const char* xwB = (const char*)xw2;
    const int laneB = lane << 3;

    float dn0 = 0.f, dn1 = 0.f, dn2 = 0.f, dn3 = 0.f;
    float ac0 = 0.f, ac1 = 0.f, ac2 = 0.f, ac3 = 0.f;

    for (int base = 0; base < deg; base += 64) {
        const int m = min(64, deg - base);
        if (lane < m) {
            const int s = esrc[row + base + lane];
            const float4 as = *reinterpret_cast<const float4*>(asrc + (size_t)s * 4);
            const float e0 = __expf(lrelu(as.x + ad.x));
            const float e1 = __expf(lrelu(as.y + ad.y));
            const float e2 = __expf(lrelu(as.z + ad.z));
            const float e3 = __expf(lrelu(as.w + ad.w));
            dn0 += e0; dn1 += e1; dn2 += e2; dn3 += e3;
            wbuf[wv][lane] = make_float4(e0, e1, e2, e3);
            sbuf[wv][lane] = s << 9;   // *512 B node row
        }
        int j = 0;
        for (; j + 4 <= m; j += 4) {
            uint2 v0 = *(const uint2*)(xwB + sbuf[wv][j]     + laneB);
            uint2 v1 = *(const uint2*)(xwB + sbuf[wv][j + 1] + laneB);
            uint2 v2 = *(const uint2*)(xwB + sbuf[wv][j + 2] + laneB);
            uint2 v3 = *(const uint2*)(xwB + sbuf[wv][j + 3] + laneB);
            {
                const float4 w = wbuf[wv][j];
                ac0 = fmaf(w.x, bflo(v0.x), ac0); ac1 = fmaf(w.y, bfhi(v0.x), ac1);
                ac2 = fmaf(w.z, bflo(v0.y), ac2); ac3 = fmaf(w.w, bfhi(v0.y), ac3);
            }
            {
                const float4 w = wbuf[wv][j + 1];
                ac0 = fmaf(w.x, bflo(v1.x), ac0); ac1 = fmaf(w.y, bfhi(v1.x), ac1);
                ac2 = fmaf(w.z, bflo(v1.y), ac2); ac3 = fmaf(w.w, bfhi(v1.y), ac3);
            }
            {
                const float4 w = wbuf[wv][j + 2];
                ac0 = fmaf(w.x, bflo(v2.x), ac0); ac1 = fmaf(w.y, bfhi(v2.x), ac1);
                ac2 = fmaf(w.z, bflo(v2.y), ac2); ac3 = fmaf(w.w, bfhi(v2.y), ac3);
            }
            {
                const float4 w = wbuf[wv][j + 3];
                ac0 = fmaf(w.x, bflo(v3.x), ac0); ac1 = fmaf(w.y, bfhi(v3.x), ac1);
                ac2 = fmaf(w.z, bflo(v3.y), ac2); ac3 = fmaf(w.w, bfhi(v3.y), ac3);
            }
        }
        for (; j < m; ++j) {
            const float4 w = wbuf[wv][j];
            const uint2 v = *(const uint2*)(xwB + sbuf[wv][j] + laneB);
            ac0 = fmaf(w.x, bflo(v.x), ac0);
            ac1 = fmaf(w.y, bfhi(v.x), ac1);
            ac2 = fmaf(w.z, bflo(v.y), ac2);
            ac3 = fmaf(w.w, bfhi(v.y), ac3);
        }
    }

    #pragma unroll
    for (int off = 32; off >= 1; off >>= 1) {
        dn0 += __shfl_xor(dn0, off);
        dn1 += __shfl_xor(dn1, off);
        dn2 += __shfl_xor(dn2, off);
        dn3 += __shfl_xor(dn3, off);
    }
    // self-loop
    const float4 asd = *reinterpret_cast<const float4*>(asrc + (size_t)d * 4);
    const float s0 = __expf(lrelu(asd.x + ad.x));
    const float s1 = __expf(lrelu(asd.y + ad.y));
    const float s2 = __expf(lrelu(asd.z + ad.z));
    const float s3 = __expf(lrelu(asd.w + ad.w));
    const uint2 u = xw2[(size_t)d * 64 + lane];
    ac0 = fmaf(s0, bflo(u.x), ac0); ac1 = fmaf(s1, bfhi(u.x), ac1);
    ac2 = fmaf(s2, bflo(u.y), ac2); ac3 = fmaf(s3, bfhi(u.y), ac3);
    const float i0 = 0.25f / (dn0 + s0);
    const float i1 = 0.25f / (dn1 + s1);
    const float i2 = 0.25f / (dn2 + s2);
    const float i3 = 0.25f / (dn3 + s3);
    const float v = ac0 * i0 + ac1 * i1 + ac2 * i2 + ac3 * i3
                  + bias[lane] + xres[(size_t)d * OUT_CH + lane];
    out[(size_t)d * OUT_CH + lane] = fmaxf(v, 0.f);
}

extern "C" void kernel_launch(void* const* d_in, const int* in_sizes, int n_in,
                              void* d_out, int out_size, void* d_ws, size_t ws_size,
                              hipStream_t stream) {
    const float* x    = (const float*)d_in[0];
    const int*   ei   = (const int*)d_in[1];
    const float* W    = (const float*)d_in[2];
    const float* attS = (const float*)d_in[3];
    const float* attD = (const float*)d_in[4];
    const float* bias = (const float*)d_in[5];
    const float* Wres = (const float*)d_in[6];
    float* out = (float*)d_out;

    char* p = (char*)d_ws;
    uint4*    Bp    = (uint4*)p;    p += (size_t)NKK * NTILES * 64 * 16;  // 160 KB
    uint2*    xw2   = (uint2*)p;    p += (size_t)N_NODES * 64 * 8;        // 25.6 MB
    float*    xres  = (float*)p;    p += (size_t)N_NODES * OUT_CH * 4;    // 12.8 MB
    float*    asrc  = (float*)p;    p += (size_t)N_NODES * HEADS * 4;
    float*    adst  = (float*)p;    p += (size_t)N_NODES * HEADS * 4;
    int*      cnt   = (int*)p;      p += (size_t)N_NODES * 4;
    int*      fill  = (int*)p;      p += (size_t)N_NODES * 4;
    int*      lscan = (int*)p;      p += (size_t)N_NODES * 4;
    int*      bsum  = (int*)p;      p += 256 * 4;
    int*      esrc  = (int*)p;      p += (size_t)N_EDGES * 4;

    hipMemsetAsync(cnt, 0, (size_t)N_NODES * sizeof(int), stream);

    prep<<<PACK_BLOCKS + (N_EDGES + 255) / 256, 256, 0, stream>>>(
        W, Wres, Bp, ei, cnt, fill);
    gemm_scan<<<GEMM_BLOCKS + SCAN_BLOCKS, 256, 0, stream>>>(
        x, Bp, xw2, xres, cnt, lscan, bsum);
    scatter_logits<<<SCAT_BLOCKS + LOGIT_BLOCKS, 256, 0, stream>>>(
        ei, lscan, bsum, fill, esrc, xw2, attS, attD, asrc, adst);
    aggregate<<<LOGIT_BLOCKS, 256, 0, stream>>>(
        esrc, lscan, bsum, cnt, asrc, adst, xw2, xres, bias, out);
}

// Round 9
// 245.842 us; speedup vs baseline: 1.1957x; 1.1957x over previous
//
#include <hip/hip_runtime.h>
#include <math.h>

#define N_NODES 50000
#define N_EDGES 800000
#define IN_CH   256
#define OUT_CH  64
#define HEADS   4
#define NEG_SLOPE 0.2f
#define NCOLS   320           // W (256) || W_res (64)
#define NTILES  20            // NCOLS / 16
#define NKK     8             // IN_CH / 32
#define PACK_BLOCKS 40        // NKK*NTILES*64 / 256
#define GEMM_BLOCKS 782       // (N_NODES+63)/64
#define SCAN_BLOCKS 196       // (N_NODES+255)/256
#define HIST_BLOCKS 3125      // N_EDGES/256
#define SCAT_BLOCKS 3125      // N_EDGES/256
#define LOGIT_BLOCKS 12500    // N_NODES/4

typedef __attribute__((ext_vector_type(8))) short short8;
typedef __attribute__((ext_vector_type(4))) float f32x4;

__device__ __forceinline__ float lrelu(float v) {
    return v > 0.f ? v : NEG_SLOPE * v;
}
__device__ __forceinline__ unsigned bf16_rne(float f) {
    unsigned u = __float_as_uint(f);
    return (u + 0x7FFFu + ((u >> 16) & 1u)) >> 16;
}
__device__ __forceinline__ unsigned pack2(float lo, float hi) {
    return bf16_rne(lo) | (bf16_rne(hi) << 16);
}
__device__ __forceinline__ float bflo(unsigned u) { return __uint_as_float(u << 16); }
__device__ __forceinline__ float bfhi(unsigned u) { return __uint_as_float(u & 0xFFFF0000u); }
__device__ __forceinline__ short8 as_short8(uint4 u) {
    union { uint4 u4; short8 s8; } cv; cv.u4 = u; return cv.s8;
}

// ---------------------------------------------------------------------------
// pack_B: [W | W_res] fp32 -> bf16 MFMA B-fragment order (tiny, 40 blocks).
// ---------------------------------------------------------------------------
__global__ __launch_bounds__(256) void pack_B(
    const float* __restrict__ W, const float* __restrict__ Wres,
    uint4* __restrict__ Bp)
{
    const int idx  = blockIdx.x * 256 + threadIdx.x;   // 0..10239
    const int kk   = idx / (NTILES * 64);
    const int rem  = idx - kk * (NTILES * 64);
    const int t    = rem >> 6;
    const int lane = rem & 63;
    const int colL = lane & 15, quad = lane >> 4;
    const int col  = t * 16 + colL;
    const int k0   = kk * 32 + quad * 8;
    float v[8];
    #pragma unroll
    for (int j = 0; j < 8; ++j) {
        const int k = k0 + j;
        v[j] = (col < IN_CH) ? W[(size_t)k * IN_CH + col]
                             : Wres[(size_t)k * OUT_CH + (col - IN_CH)];
    }
    uint4 u;
    u.x = pack2(v[0], v[1]); u.y = pack2(v[2], v[3]);
    u.z = pack2(v[4], v[5]); u.w = pack2(v[6], v[7]);
    Bp[(kk * NTILES + t) * 64 + lane] = u;
}

// ---------------------------------------------------------------------------
// hist_gemm: fused independent halves.
//   blocks [0, GEMM_BLOCKS)          : MFMA node transform
//   blocks [GEMM_BLOCKS,+HIST_BLOCKS): histogram with POSITION CAPTURE —
//     epos[e] = atomicAdd(&cnt[d],1). The atomic's return value is the
//     edge's slot within its dst row, so the later scatter needs NO atomic.
// gemm: wave wv owns col-tiles {wv,4+wv,8+wv,12+wv,16+wv} over 4 row-groups;
// C/D: col=lane&15, row=(lane>>4)*4+reg. xw2 uint2 = (h0,h1|h2,h3) bf16.
// ---------------------------------------------------------------------------
__global__ __launch_bounds__(256) void hist_gemm(
    const float* __restrict__ x, const uint4* __restrict__ Bp,
    uint2* __restrict__ xw2, float* __restrict__ xres,
    const int* __restrict__ ei, int* __restrict__ cnt,
    int* __restrict__ epos)
{
    __shared__ uint4 Alds[4 * NKK * 64];   // 32 KB

    if (blockIdx.x >= GEMM_BLOCKS) {
        const int e = (blockIdx.x - GEMM_BLOCKS) * 256 + threadIdx.x;
        if (e < N_EDGES)
            epos[e] = atomicAdd(&cnt[ei[N_EDGES + e]], 1);
        return;
    }

    const int tid = threadIdx.x;
    const int n0  = blockIdx.x * 64;

    #pragma unroll
    for (int i = 0; i < 8; ++i) {
        const int e    = i * 256 + tid;
        const int g    = e >> 9;
        const int kk   = (e >> 6) & 7;
        const int lane = e & 63;
        const int cL   = lane & 15, qd = lane >> 4;
        const int row  = n0 + g * 16 + cL;
        const int k0   = kk * 32 + qd * 8;
        uint4 u = make_uint4(0u, 0u, 0u, 0u);
        if (row < N_NODES) {
            const float4 a = *reinterpret_cast<const float4*>(x + (size_t)row * IN_CH + k0);
            const float4 b = *reinterpret_cast<const float4*>(x + (size_t)row * IN_CH + k0 + 4);
            u.x = pack2(a.x, a.y); u.y = pack2(a.z, a.w);
            u.z = pack2(b.x, b.y); u.w = pack2(b.z, b.w);
        }
        Alds[(g * NKK + kk) * 64 + lane] = u;
    }
    __syncthreads();

    const int lane = tid & 63;
    const int wv   = tid >> 6;
    const int colL = lane & 15, quad = lane >> 4;

    f32x4 acc[4][5];
    #pragma unroll
    for (int rg = 0; rg < 4; ++rg)
        #pragma unroll
        for (int j = 0; j < 5; ++j) acc[rg][j] = (f32x4){0.f, 0.f, 0.f, 0.f};

    for (int kk = 0; kk < NKK; ++kk) {
        uint4 bu[5];
        #pragma unroll
        for (int j = 0; j < 5; ++j)
            bu[j] = Bp[(kk * NTILES + j * 4 + wv) * 64 + lane];
        #pragma unroll
        for (int rg = 0; rg < 4; ++rg) {
            const short8 a = as_short8(Alds[(rg * NKK + kk) * 64 + lane]);
            #pragma unroll
            for (int j = 0; j < 5; ++j)
                acc[rg][j] = __builtin_amdgcn_mfma_f32_16x16x32_bf16(
                    a, as_short8(bu[j]), acc[rg][j], 0, 0, 0);
        }
    }

    #pragma unroll
    for (int rg = 0; rg < 4; ++rg) {
        #pragma unroll
        for (int r = 0; r < 4; ++r) {
            const int row = n0 + rg * 16 + quad * 4 + r;
            if (row < N_NODES) {
                xw2[(size_t)row * 64 + wv * 16 + colL] = make_uint2(
                    pack2(acc[rg][0][r], acc[rg][1][r]),
                    pack2(acc[rg][2][r], acc[rg][3][r]));
                xres[(size_t)row * OUT_CH + wv * 16 + colL] = acc[rg][4][r];
            }
        }
    }
}

// ---------------------------------------------------------------------------
// scan_local: per-256-chunk exclusive scan of cnt; block sums to bsum.
// Consumers inline the 196-element bsum scan (L2-hot).
// ---------------------------------------------------------------------------
__global__ __launch_bounds__(256) void scan_local(
    const int* __restrict__ cnt, int* __restrict__ lscan, int* __restrict__ bsum)
{
    __shared__ int ws[4];
    const int t = threadIdx.x, lane = t & 63, w = t >> 6;
    const int i = blockIdx.x * 256 + t;
    const int v = (i < N_NODES) ? cnt[i] : 0;
    int sc = v;
    #pragma unroll
    for (int off = 1; off < 64; off <<= 1) {
        const int n = __shfl_up(sc, off);
        if (lane >= off) sc += n;
    }
    if (lane == 63) ws[w] = sc;
    __syncthreads();
    int prefix = 0;
    for (int j = 0; j < w; ++j) prefix += ws[j];
    if (i < N_NODES) lscan[i] = prefix + sc - v;
    if (t == 255) bsum[blockIdx.x] = prefix + sc;
}

// ---------------------------------------------------------------------------
// scatter_logits: fused independent halves.
//   blocks [0,SCAT_BLOCKS): ATOMIC-FREE scatter — slot comes from epos[e]
//     captured during the histogram. Coalesced reads + one random write.
//   blocks [SCAT_BLOCKS,+LOGIT_BLOCKS): attention logits from packed xw2.
// ---------------------------------------------------------------------------
__global__ __launch_bounds__(256) void scatter_logits(
    const int* __restrict__ ei, const int* __restrict__ epos,
    const int* __restrict__ lscan, const int* __restrict__ bsum,
    int* __restrict__ esrc,
    const uint2* __restrict__ xw2, const float* __restrict__ attS,
    const float* __restrict__ attD, float* __restrict__ asrc,
    float* __restrict__ adst)
{
    const int t = threadIdx.x;
    const int lane = t & 63, wv = t >> 6;

    if (blockIdx.x < SCAT_BLOCKS) {
        __shared__ int bsx[256];
        __shared__ int ws[4];
        const int v = (t < SCAN_BLOCKS) ? bsum[t] : 0;
        int sc = v;
        #pragma unroll
        for (int off = 1; off < 64; off <<= 1) {
            const int n = __shfl_up(sc, off);
            if (lane >= off) sc += n;
        }
        if (lane == 63) ws[wv] = sc;
        __syncthreads();
        int prefix = 0;
        for (int j = 0; j < wv; ++j) prefix += ws[j];
        bsx[t] = prefix + sc - v;
        __syncthreads();

        const int e = blockIdx.x * 256 + t;
        if (e < N_EDGES) {
            const int d = ei[N_EDGES + e];
            esrc[lscan[d] + bsx[d >> 8] + epos[e]] = ei[e];
        }
        return;
    }

    // ---- logits: one wave per node ----
    const int n = (blockIdx.x - SCAT_BLOCKS) * 4 + wv;   // 12500*4 = 50000
    const uint2 v = xw2[(size_t)n * 64 + lane];
    const float h0 = bflo(v.x), h1 = bfhi(v.x), h2 = bflo(v.y), h3 = bfhi(v.y);
    float s0 = h0 * attS[lane],       s1 = h1 * attS[64 + lane];
    float s2 = h2 * attS[128 + lane], s3 = h3 * attS[192 + lane];
    float d0 = h0 * attD[lane],       d1 = h1 * attD[64 + lane];
    float d2 = h2 * attD[128 + lane], d3 = h3 * attD[192 + lane];
    #pragma unroll
    for (int off = 32; off >= 1; off >>= 1) {
        s0 += __shfl_xor(s0, off); s1 += __shfl_xor(s1, off);
        s2 += __shfl_xor(s2, off); s3 += __shfl_xor(s3, off);
        d0 += __shfl_xor(d0, off); d1 += __shfl_xor(d1, off);
        d2 += __shfl_xor(d2, off); d3 += __shfl_xor(d3, off);
    }
    if (lane == 0)
        *reinterpret_cast<float4*>(asrc + (size_t)n * 4) = make_float4(s0, s1, s2, s3);
    if (lane == 1)
        *reinterpret_cast<float4*>(adst + (size_t)n * 4) = make_float4(d0, d1, d2, d3);
}

// ---------------------------------------------------------------------------
// aggregate, single-pass, unnormalized head accumulators. Inline bsum scan.
// Per 64-edge chunk: lane-parallel gather asrc + exp -> LDS stash; per edge:
// uniform-addr LDS broadcast + ONE dwordx2 gather + 4 fma. 4x unroll, live
// regs kept low (latency-bound: occupancy > ILP — R6 lesson).
// ---------------------------------------------------------------------------
__global__ __launch_bounds__(256) void aggregate(
    const int* __restrict__ esrc, const int* __restrict__ lscan,
    const int* __restrict__ bsum, const int* __restrict__ cnt,
    const float* __restrict__ asrc, const float* __restrict__ adst,
    const uint2* __restrict__ xw2, const float* __restrict__ xres,
    const float* __restrict__ bias, float* __restrict__ out)
{
    __shared__ float4 wbuf[4][64];
    __shared__ int    sbuf[4][64];
    __shared__ int    bsx[256];
    __shared__ int    ws[4];
    const int t = threadIdx.x;
    const int lane = t & 63;
    const int wv   = t >> 6;

    {
        const int v = (t < SCAN_BLOCKS) ? bsum[t] : 0;
        int sc = v;
        #pragma unroll
        for (int off = 1; off < 64; off <<= 1) {
            const int n = __shfl_up(sc, off);
            if (lane >= off) sc += n;
        }
        if (lane == 63) ws[wv] = sc;
        __syncthreads();
        int prefix = 0;
        for (int j = 0; j < wv; ++j) prefix += ws[j];
        bsx[t] = prefix + sc - v;
        __syncthreads();
    }

    const int d = blockIdx.x * 4 + wv;                   // 12500*4 = 50000
    const int row = lscan[d] + bsx[d >> 8];
    const int deg = cnt[d];
    const float4 ad = *reinterpret_cast<const float4*>(adst + (size_t)d * 4);
    const char* xwB = (const char*)xw2;
    const int laneB = lane << 3;

    float dn0 = 0.f, dn1 = 0.f, dn2 = 0.f, dn3 = 0.f;
    float ac0 = 0.f, ac1 = 0.f, ac2 = 0.f, ac3 = 0.f;

    for (int base = 0; base < deg; base += 64) {
        const int m = min(64, deg - base);
        if (lane < m) {
            const int s = esrc[row + base + lane];
            const float4 as = *reinterpret_cast<const float4*>(asrc + (size_t)s * 4);
            const float e0 = __expf(lrelu(as.x + ad.x));
            const float e1 = __expf(lrelu(as.y + ad.y));
            const float e2 = __expf(lrelu(as.z + ad.z));
            const float e3 = __expf(lrelu(as.w + ad.w));
            dn0 += e0; dn1 += e1; dn2 += e2; dn3 += e3;
            wbuf[wv][lane] = make_float4(e0, e1, e2, e3);
            sbuf[wv][lane] = s << 9;   // *512 B node row
        }
        int j = 0;
        for (; j + 4 <= m; j += 4) {
            uint2 v0 = *(const uint2*)(xwB + sbuf[wv][j]     + laneB);
            uint2 v1 = *(const uint2*)(xwB + sbuf[wv][j + 1] + laneB);
            uint2 v2 = *(const uint2*)(xwB + sbuf[wv][j + 2] + laneB);
            uint2 v3 = *(const uint2*)(xwB + sbuf[wv][j + 3] + laneB);
            {
                const float4 w = wbuf[wv][j];
                ac0 = fmaf(w.x, bflo(v0.x), ac0); ac1 = fmaf(w.y, bfhi(v0.x), ac1);
                ac2 = fmaf(w.z, bflo(v0.y), ac2); ac3 = fmaf(w.w, bfhi(v0.y), ac3);
            }
            {
                const float4 w = wbuf[wv][j + 1];
                ac0 = fmaf(w.x, bflo(v1.x), ac0); ac1 = fmaf(w.y, bfhi(v1.x), ac1);
                ac2 = fmaf(w.z, bflo(v1.y), ac2); ac3 = fmaf(w.w, bfhi(v1.y), ac3);
            }
            {
                const float4 w = wbuf[wv][j + 2];
                ac0 = fmaf(w.x, bflo(v2.x), ac0); ac1 = fmaf(w.y, bfhi(v2.x), ac1);
                ac2 = fmaf(w.z, bflo(v2.y), ac2); ac3 = fmaf(w.w, bfhi(v2.y), ac3);
            }
            {
                const float4 w = wbuf[wv][j + 3];
                ac0 = fmaf(w.x, bflo(v3.x), ac0); ac1 = fmaf(w.y, bfhi(v3.x), ac1);
                ac2 = fmaf(w.z, bflo(v3.y), ac2); ac3 = fmaf(w.w, bfhi(v3.y), ac3);
            }
        }
        for (; j < m; ++j) {
            const float4 w = wbuf[wv][j];
            const uint2 v = *(const uint2*)(xwB + sbuf[wv][j] + laneB);
            ac0 = fmaf(w.x, bflo(v.x), ac0);
            ac1 = fmaf(w.y, bfhi(v.x), ac1);
            ac2 = fmaf(w.z, bflo(v.y), ac2);
            ac3 = fmaf(w.w, bfhi(v.y), ac3);
        }
    }

    #pragma unroll
    for (int off = 32; off >= 1; off >>= 1) {
        dn0 += __shfl_xor(dn0, off);
        dn1 += __shfl_xor(dn1, off);
        dn2 += __shfl_xor(dn2, off);
        dn3 += __shfl_xor(dn3, off);
    }
    // self-loop
    const float4 asd = *reinterpret_cast<const float4*>(asrc + (size_t)d * 4);
    const float s0 = __expf(lrelu(asd.x + ad.x));
    const float s1 = __expf(lrelu(asd.y + ad.y));
    const float s2 = __expf(lrelu(asd.z + ad.z));
    const float s3 = __expf(lrelu(asd.w + ad.w));
    const uint2 u = xw2[(size_t)d * 64 + lane];
    ac0 = fmaf(s0, bflo(u.x), ac0); ac1 = fmaf(s1, bfhi(u.x), ac1);
    ac2 = fmaf(s2, bflo(u.y), ac2); ac3 = fmaf(s3, bfhi(u.y), ac3);
    const float i0 = 0.25f / (dn0 + s0);
    const float i1 = 0.25f / (dn1 + s1);
    const float i2 = 0.25f / (dn2 + s2);
    const float i3 = 0.25f / (dn3 + s3);
    const float v = ac0 * i0 + ac1 * i1 + ac2 * i2 + ac3 * i3
                  + bias[lane] + xres[(size_t)d * OUT_CH + lane];
    out[(size_t)d * OUT_CH + lane] = fmaxf(v, 0.f);
}

extern "C" void kernel_launch(void* const* d_in, const int* in_sizes, int n_in,
                              void* d_out, int out_size, void* d_ws, size_t ws_size,
                              hipStream_t stream) {
    const float* x    = (const float*)d_in[0];
    const int*   ei   = (const int*)d_in[1];
    const float* W    = (const float*)d_in[2];
    const float* attS = (const float*)d_in[3];
    const float* attD = (const float*)d_in[4];
    const float* bias = (const float*)d_in[5];
    const float* Wres = (const float*)d_in[6];
    float* out = (float*)d_out;

    char* p = (char*)d_ws;
    uint4*    Bp    = (uint4*)p;    p += (size_t)NKK * NTILES * 64 * 16;  // 160 KB
    uint2*    xw2   = (uint2*)p;    p += (size_t)N_NODES * 64 * 8;        // 25.6 MB
    float*    xres  = (float*)p;    p += (size_t)N_NODES * OUT_CH * 4;    // 12.8 MB
    float*    asrc  = (float*)p;    p += (size_t)N_NODES * HEADS * 4;
    float*    adst  = (float*)p;    p += (size_t)N_NODES * HEADS * 4;
    int*      cnt   = (int*)p;      p += (size_t)N_NODES * 4;
    int*      lscan = (int*)p;      p += (size_t)N_NODES * 4;
    int*      bsum  = (int*)p;      p += 256 * 4;
    int*      epos  = (int*)p;      p += (size_t)N_EDGES * 4;
    int*      esrc  = (int*)p;      p += (size_t)N_EDGES * 4;

    hipMemsetAsync(cnt, 0, (size_t)N_NODES * sizeof(int), stream);

    pack_B<<<PACK_BLOCKS, 256, 0, stream>>>(W, Wres, Bp);
    hist_gemm<<<GEMM_BLOCKS + HIST_BLOCKS, 256, 0, stream>>>(
        x, Bp, xw2, xres, ei, cnt, epos);
    scan_local<<<SCAN_BLOCKS, 256, 0, stream>>>(cnt, lscan, bsum);
    scatter_logits<<<SCAT_BLOCKS + LOGIT_BLOCKS, 256, 0, stream>>>(
        ei, epos, lscan, bsum, esrc, xw2, attS, attD, asrc, adst);
    aggregate<<<LOGIT_BLOCKS, 256, 0, stream>>>(
        esrc, lscan, bsum, cnt, asrc, adst, xw2, xres, bias, out);
}